// Round 5
// baseline (403.753 us; speedup 1.0000x reference)
//
#include <hip/hip_runtime.h>
#include <stdint.h>

#define S_DIM 8192
#define K_DIM 4096
#define N_DIM 4096

#define BM 128
#define BN 256
#define BK 128   // bytes of K per staging stage (4 MFMA k-steps of 32)

typedef int v4i  __attribute__((ext_vector_type(4)));
typedef int v16i __attribute__((ext_vector_type(16)));

// ---------------------------------------------------------------------------
// One launch: pack x (int32->int8), pack w, and copy scale_y to the output
// tail. Pack destination is contiguous in ws: [x packed | w packed].
__global__ void prep(const int* __restrict__ x, const int* __restrict__ w,
                     const float* __restrict__ sy,
                     int* __restrict__ dst, float* __restrict__ out) {
    const int nx = S_DIM * K_DIM / 4;
    const int nw = N_DIM * K_DIM / 4;
    int i = blockIdx.x * 256 + threadIdx.x;
    if (i < nx) {
        int4 a = ((const int4*)x)[i];
        dst[i] = (a.x & 0xFF) | ((a.y & 0xFF) << 8) | ((a.z & 0xFF) << 16)
               | ((a.w & 0xFF) << 24);
    } else if (i < nx + nw) {
        int4 a = ((const int4*)w)[i - nx];
        dst[i] = (a.x & 0xFF) | ((a.y & 0xFF) << 8) | ((a.z & 0xFF) << 16)
               | ((a.w & 0xFF) << 24);
    } else {
        int j = i - nx - nw;
        if (j < S_DIM) out[(size_t)S_DIM * N_DIM + j] = sy[j];
    }
}

// scale_y tail only (used by the no-workspace fallback path)
__global__ void copy_sy(const float* __restrict__ sy, float* __restrict__ out) {
    int i = blockIdx.x * blockDim.x + threadIdx.x;
    if (i < S_DIM) out[(size_t)S_DIM * N_DIM + i] = sy[i];
}

// ---------------------------------------------------------------------------
__device__ __forceinline__ void g2lds16(const void* g, void* l) {
    __builtin_amdgcn_global_load_lds((const __attribute__((address_space(1))) void*)g,
                                     (__attribute__((address_space(3))) void*)l,
                                     16, 0, 0);
}

// ---------------------------------------------------------------------------
// 128x256 tile i8 MFMA GEMM. Staging / LDS image / XOR swizzle / barrier
// structure byte-identical to the proven 131-us R0 kernel (4 waves 2x2, each
// wave 64m x 128n, global_load_lds w=16, 2 blocks/CU). R5 change: MFMA shape
// 16x16x64 -> 32x32x32 (wave tile = 2x4 tiles of 32x32; acc 8 x v16i = same
// 128 AGPRs; rate 3944 -> 4404 TOPS) with 32-B k-steps. Why: R4 proved
// frag double-buffering at 64-B k-steps needs +48 VGPR and 108+48+128 > 256
// (the 2-waves/SIMD unified-file wall) -> compiler must re-serialize the LDS
// reads against the MFMAs (131 us = 70 MFMA + 61 LDS, fully serial). At 32-B
// k-steps the live frag set halves (6 x v4i = 24 regs), so the ks/ks+1
// ping-pong fits in the SAME envelope -> per-kstep 6 ds_read_b128 (~72 cyc)
// drain under 8 MFMAs (~73 cyc): balanced overlap with zero VGPR growth.
//
// LDS layout (unchanged, measured 0 conflicts): rows 128 B = 8 chunks of
// 16 B; chunk c of row r lives at slot c ^ (r&7). Fragment reads stay
// 2-lanes-per-slot within every 16-lane quarter (same pattern class R0
// verified). global_load_lds writes LDS linearly with the inverse
// permutation on the global source address (both-sides-or-neither).
__launch_bounds__(256, 2)
__global__ void gemm_i8(const signed char* __restrict__ xp,
                        const signed char* __restrict__ wp,
                        const float* __restrict__ sx,
                        const float* __restrict__ sw,
                        const float* __restrict__ sy,
                        float* __restrict__ out) {
    __shared__ __align__(16) signed char As[BM * BK];   // 16 KB
    __shared__ __align__(16) signed char Bs[BN * BK];   // 32 KB

    const int tid  = threadIdx.x;
    const int lane = tid & 63;
    const int r32  = lane & 31;    // row (A) / col (B) within a 32-tile
    const int h    = lane >> 5;    // which 16B half of the 32B k-step
    const int c7   = lane & 7;     // swizzle component (row & 7)
    const int wave = tid >> 6;     // 0..3
    const int wm = wave >> 1;      // wave m (2): 64-row slab
    const int wn = wave & 1;       // wave n (2): 128-col slab
    const int bn = blockIdx.x;     // fast axis
    const int bm = blockIdx.y;

    const signed char* aG = xp + (size_t)(bm * BM) * K_DIM;
    const signed char* bG = wp + (size_t)(bn * BN) * K_DIM;

    // Hoisted per-thread staging offsets (loop-invariant): A = 1024 chunks,
    // B = 2048 chunks of 16B; thread handles 4 A + 8 B chunks per stage.
    int aOff[4], bOff[8];
#pragma unroll
    for (int i = 0; i < 4; i++) {
        int li = i * 256 + tid;
        int row = li >> 3, c = li & 7, g = c ^ (row & 7);
        aOff[i] = row * K_DIM + (g << 4);
    }
#pragma unroll
    for (int i = 0; i < 8; i++) {
        int li = i * 256 + tid;
        int row = li >> 3, c = li & 7, g = c ^ (row & 7);
        bOff[i] = row * K_DIM + (g << 4);
    }

    // Fragment read: for k-step ks (0..3), this lane reads 16B chunk
    // (ks*2 + h) of its row, at swizzled slot ((ks<<1)|h) ^ (row&7).
    // Row bases are multiples of 32 -> row&7 == lane&7. Loop-invariant.
    int o[4];
#pragma unroll
    for (int ks = 0; ks < 4; ks++)
        o[ks] = ((((ks << 1) | h) ^ c7) << 4);

    const signed char* aB0 = As + (wm * 64 +  0 + r32) * BK;
    const signed char* aB1 = As + (wm * 64 + 32 + r32) * BK;
    const signed char* bB0 = Bs + (wn * 128 +  0 + r32) * BK;
    const signed char* bB1 = Bs + (wn * 128 + 32 + r32) * BK;
    const signed char* bB2 = Bs + (wn * 128 + 64 + r32) * BK;
    const signed char* bB3 = Bs + (wn * 128 + 96 + r32) * BK;

    v16i acc[2][4];
#pragma unroll
    for (int i = 0; i < 2; i++)
#pragma unroll
        for (int j = 0; j < 4; j++) acc[i][j] = 0;

    for (int kk = 0; kk < K_DIM; kk += BK) {
        __syncthreads();  // protect LDS from previous iteration's readers
#pragma unroll
        for (int i = 0; i < 4; i++)
            g2lds16(aG + aOff[i] + kk, As + (i * 256 + tid) * 16);
#pragma unroll
        for (int i = 0; i < 8; i++)
            g2lds16(bG + bOff[i] + kk, Bs + (i * 256 + tid) * 16);
        __syncthreads();  // vmcnt(0) drain: staging complete

        // 4 k-steps of 32B; fragments ping-pong so k-step ks+1's 6
        // ds_read_b128 drain under k-step ks's 8 MFMAs (counted lgkmcnt).
        v4i af[2][2], bf[2][4];
        af[0][0] = *(const v4i*)(aB0 + o[0]);
        af[0][1] = *(const v4i*)(aB1 + o[0]);
        bf[0][0] = *(const v4i*)(bB0 + o[0]);
        bf[0][1] = *(const v4i*)(bB1 + o[0]);
        bf[0][2] = *(const v4i*)(bB2 + o[0]);
        bf[0][3] = *(const v4i*)(bB3 + o[0]);
#pragma unroll
        for (int ks = 0; ks < 4; ks++) {
            const int cur = ks & 1, nxt = cur ^ 1;
            if (ks < 3) {
                af[nxt][0] = *(const v4i*)(aB0 + o[ks + 1]);
                af[nxt][1] = *(const v4i*)(aB1 + o[ks + 1]);
                bf[nxt][0] = *(const v4i*)(bB0 + o[ks + 1]);
                bf[nxt][1] = *(const v4i*)(bB1 + o[ks + 1]);
                bf[nxt][2] = *(const v4i*)(bB2 + o[ks + 1]);
                bf[nxt][3] = *(const v4i*)(bB3 + o[ks + 1]);
            }
#pragma unroll
            for (int mt = 0; mt < 2; mt++)
#pragma unroll
                for (int nt = 0; nt < 4; nt++)
                    acc[mt][nt] = __builtin_amdgcn_mfma_i32_32x32x32_i8(
                        af[cur][mt], bf[cur][nt], acc[mt][nt], 0, 0, 0);
        }
    }

    // Epilogue. 32x32 C/D layout: col = lane&31,
    // row = (reg&3) + 8*(reg>>2) + 4*(lane>>5)  (guide, m74/m101).
    const int s_base = bm * BM + wm * 64;
    const int n_base = bn * BN + wn * 128;
    float swv[4];
#pragma unroll
    for (int nt = 0; nt < 4; nt++) swv[nt] = sw[n_base + nt * 32 + r32];
#pragma unroll
    for (int mt = 0; mt < 2; mt++) {
#pragma unroll
        for (int q = 0; q < 4; q++) {
#pragma unroll
            for (int rr = 0; rr < 4; rr++) {
                int s = s_base + mt * 32 + q * 8 + h * 4 + rr;
                float rs = sx[s] / sy[s];
                float* orow = out + (size_t)s * N_DIM;
#pragma unroll
                for (int nt = 0; nt < 4; nt++) {
                    int n = n_base + nt * 32 + r32;
                    float v = rintf((float)acc[mt][nt][q * 4 + rr]
                                    * (rs * swv[nt]));
                    v = fminf(fmaxf(v, -128.f), 127.f);
                    orow[n] = v;
                }
            }
        }
    }
}

// ---------------------------------------------------------------------------
// Correctness fallback if the workspace is too small for packed operands.
__global__ void gemm_naive(const int* __restrict__ x, const int* __restrict__ w,
                           const float* __restrict__ sx, const float* __restrict__ sw,
                           const float* __restrict__ sy, float* __restrict__ out) {
    int n = blockIdx.x * blockDim.x + threadIdx.x;
    int s = blockIdx.y;
    const int4* xr = (const int4*)(x + (size_t)s * K_DIM);
    const int4* wr = (const int4*)(w + (size_t)n * K_DIM);
    int acc = 0;
    for (int k = 0; k < K_DIM / 4; k++) {
        int4 a = xr[k], b = wr[k];
        acc += a.x * b.x + a.y * b.y + a.z * b.z + a.w * b.w;
    }
    float v = rintf((float)acc * (sx[s] / sy[s] * sw[n]));
    out[(size_t)s * N_DIM + n] = fminf(fmaxf(v, -128.f), 127.f);
}

// ---------------------------------------------------------------------------
extern "C" void kernel_launch(void* const* d_in, const int* in_sizes, int n_in,
                              void* d_out, int out_size, void* d_ws, size_t ws_size,
                              hipStream_t stream) {
    const int*   x  = (const int*)d_in[0];     // [S, K] int8 values widened to int32
    const int*   wq = (const int*)d_in[1];     // [N, K]
    const float* sx = (const float*)d_in[2];   // [S]
    const float* sw = (const float*)d_in[3];   // [N]
    const float* sy = (const float*)d_in[4];   // [S]
    float* out = (float*)d_out;                // [S*N out_q] ++ [S scale_y], float32

    const size_t need = (size_t)S_DIM * K_DIM + (size_t)N_DIM * K_DIM;  // 48 MiB
    if (ws_size >= need) {
        signed char* xp = (signed char*)d_ws;
        signed char* wp = xp + (size_t)S_DIM * K_DIM;
        const int nprep = (S_DIM * K_DIM / 4) + (N_DIM * K_DIM / 4) + S_DIM;
        prep<<<dim3((nprep + 255) / 256), dim3(256), 0, stream>>>(
            x, wq, sy, (int*)xp, out);
        gemm_i8<<<dim3(N_DIM / BN, S_DIM / BM), dim3(256), 0, stream>>>(
            xp, wp, sx, sw, sy, out);
    } else {
        copy_sy<<<dim3((S_DIM + 255) / 256), dim3(256), 0, stream>>>(sy, out);
        gemm_naive<<<dim3(N_DIM / 256, S_DIM), dim3(256), 0, stream>>>(
            x, wq, sx, sw, sy, out);
    }
}

// Round 6
// 402.155 us; speedup vs baseline: 1.0040x; 1.0040x over previous
//
#include <hip/hip_runtime.h>
#include <stdint.h>

#define S_DIM 8192
#define K_DIM 4096
#define N_DIM 4096

#define BM 128
#define BN 256
#define BKB 64               // bytes of K per stage = ONE 16x16x64 k-step
#define NT (K_DIM / BKB)     // 64 stages

typedef int v4i __attribute__((ext_vector_type(4)));

// ---------------------------------------------------------------------------
// One launch: pack x (int32->int8), pack w, and copy scale_y to the output
// tail. Pack destination is contiguous in ws: [x packed | w packed].
__global__ void prep(const int* __restrict__ x, const int* __restrict__ w,
                     const float* __restrict__ sy,
                     int* __restrict__ dst, float* __restrict__ out) {
    const int nx = S_DIM * K_DIM / 4;
    const int nw = N_DIM * K_DIM / 4;
    int i = blockIdx.x * 256 + threadIdx.x;
    if (i < nx) {
        int4 a = ((const int4*)x)[i];
        dst[i] = (a.x & 0xFF) | ((a.y & 0xFF) << 8) | ((a.z & 0xFF) << 16)
               | ((a.w & 0xFF) << 24);
    } else if (i < nx + nw) {
        int4 a = ((const int4*)w)[i - nx];
        dst[i] = (a.x & 0xFF) | ((a.y & 0xFF) << 8) | ((a.z & 0xFF) << 16)
               | ((a.w & 0xFF) << 24);
    } else {
        int j = i - nx - nw;
        if (j < S_DIM) out[(size_t)S_DIM * N_DIM + j] = sy[j];
    }
}

// scale_y tail only (used by the no-workspace fallback path)
__global__ void copy_sy(const float* __restrict__ sy, float* __restrict__ out) {
    int i = blockIdx.x * blockDim.x + threadIdx.x;
    if (i < S_DIM) out[(size_t)S_DIM * N_DIM + i] = sy[i];
}

// ---------------------------------------------------------------------------
__device__ __forceinline__ void g2lds16(const void* g, void* l) {
    __builtin_amdgcn_global_load_lds((const __attribute__((address_space(1))) void*)g,
                                     (__attribute__((address_space(3))) void*)l,
                                     16, 0, 0);
}

// ---------------------------------------------------------------------------
// 128x256 tile i8 MFMA GEMM. 4 waves 2x2, each wave 64m x 128n as 4x8 tiles
// of mfma_i32_16x16x64_i8 (the proven R0 shape; R5's 32x32 variant hit
// unexplained 4-way LDS read conflicts and is reverted).
//
// R6 change: classic 2-deep LDS double-buffer, BKB=64, ONE __syncthreads per
// stage. R0 issued its stage and immediately drained it (stage ->
// sync/vmcnt(0)), exposing the DMA's L2/HBM latency serially EVERY stage and
// forcing stage/compute to fully serialize (measured: 131 us = 70 us MFMA
// floor + ~61 us LDS reads, an exact sum). Here stage t+1 is issued after
// the fragment reads of t and flies under t's 32 MFMAs; the single closing
// __syncthreads (vmcnt0+lgkmcnt0+barrier) then (a) proves all waves are done
// reading buf[cur] and (b) drains a DMA that has already had ~1000 cycles of
// flight. LDS = 2 x 24 KB = 48 KB -> still 2 blocks/CU. Fragment registers
// unchanged (12 x v4i) -> no R3/R4-style register-wall violation.
//
// LDS swizzle = R3's (measured absmax=0, 0 bank conflicts on THIS read
// pattern): 64-B rows; row pairs form 128-B super-rows of 8 16B chunks;
// chunk p of super-row s lives at slot p ^ (s&7). Fragment ds_read_b128 is
// 2-lanes/bank-group per quarter-wave = conflict-free. global_load_lds
// writes LDS linearly with the INVERSE permutation applied to the per-lane
// global source address (both-sides-or-neither rule).
__launch_bounds__(256, 2)
__global__ void gemm_i8(const signed char* __restrict__ xp,
                        const signed char* __restrict__ wp,
                        const float* __restrict__ sx,
                        const float* __restrict__ sw,
                        const float* __restrict__ sy,
                        float* __restrict__ out) {
    __shared__ __align__(16) signed char As[2][BM * BKB];   // 2 x 8 KB
    __shared__ __align__(16) signed char Bs[2][BN * BKB];   // 2 x 16 KB

    const int tid  = threadIdx.x;
    const int lane = tid & 63;
    const int quad = lane >> 4;    // 16B k-chunk within the 64B k-step
    const int l16  = lane & 15;    // row (A) / col (B) within 16
    const int wave = tid >> 6;     // 0..3
    const int wm = wave >> 1;      // 64-row slab
    const int wn = wave & 1;       // 128-col slab
    const int bn = blockIdx.x;     // fast axis
    const int bm = blockIdx.y;

    const signed char* aG = xp + (size_t)(bm * BM) * K_DIM;
    const signed char* bG = wp + (size_t)(bn * BN) * K_DIM;

    // Staging source offsets. Per stage: A = 512 chunks (2/thread),
    // B = 1024 chunks (4/thread). LDS chunk L: super-row s=L>>3, slot=L&7,
    // global chunk p = slot^(s&7) -> row = 2s+(p>>2), kchunk = p&3.
    int aOff[2], bOff[4];
#pragma unroll
    for (int i = 0; i < 2; i++) {
        int L = i * 256 + tid;
        int s = L >> 3, p = (L & 7) ^ (s & 7);
        aOff[i] = (2 * s + (p >> 2)) * K_DIM + ((p & 3) << 4);
    }
#pragma unroll
    for (int i = 0; i < 4; i++) {
        int L = i * 256 + tid;
        int s = L >> 3, p = (L & 7) ^ (s & 7);
        bOff[i] = (2 * s + (p >> 2)) * K_DIM + ((p & 3) << 4);
    }

    // Fragment read offset for (row = base16 + l16, chunk = quad):
    // byte = base16*64 + (l16>>1)*128 + ((((l16&1)<<2)|quad)^(l16>>1))*16.
    const int rdo = ((l16 >> 1) * 128)
                  + (((((l16 & 1) << 2) | quad) ^ (l16 >> 1)) << 4);

#define STAGE(T, SL) do { const int kk_ = (T) * BKB;                        \
        signed char* da_ = &As[SL][0];                                      \
        signed char* db_ = &Bs[SL][0];                                      \
        g2lds16(aG + aOff[0] + kk_, da_ + tid * 16);                        \
        g2lds16(aG + aOff[1] + kk_, da_ + 4096 + tid * 16);                 \
        g2lds16(bG + bOff[0] + kk_, db_ + tid * 16);                        \
        g2lds16(bG + bOff[1] + kk_, db_ + 4096 + tid * 16);                 \
        g2lds16(bG + bOff[2] + kk_, db_ + 8192 + tid * 16);                 \
        g2lds16(bG + bOff[3] + kk_, db_ + 12288 + tid * 16);                \
    } while (0)

    v4i acc[4][8];
#pragma unroll
    for (int i = 0; i < 4; i++)
#pragma unroll
        for (int j = 0; j < 8; j++) acc[i][j] = 0;

    // Prologue: stage 0 and drain it (one-time cold-start cost).
    STAGE(0, 0);
    __syncthreads();

    for (int t = 0; t < NT; ++t) {
        const int cur = t & 1;
        const signed char* a_lds = &As[cur][0] + wm * 4096 + rdo;
        const signed char* b_lds = &Bs[cur][0] + wn * 8192 + rdo;

        // Fragment reads first (MFMA critical path)...
        v4i af[4], bf[8];
#pragma unroll
        for (int mt = 0; mt < 4; mt++)
            af[mt] = *(const v4i*)(a_lds + mt * 1024);
#pragma unroll
        for (int nt = 0; nt < 8; nt++)
            bf[nt] = *(const v4i*)(b_lds + nt * 1024);

        // ...then issue next stage into the other buffer; its DMA flies
        // under the 32 MFMAs below. Safe: buf[cur^1] was last read in
        // iteration t-1, and every wave passed t-1's closing barrier
        // (which includes lgkmcnt(0)) to get here.
        if (t + 1 < NT) STAGE(t + 1, cur ^ 1);

#pragma unroll
        for (int mt = 0; mt < 4; mt++)
#pragma unroll
            for (int nt = 0; nt < 8; nt++)
                acc[mt][nt] = __builtin_amdgcn_mfma_i32_16x16x64_i8(
                    af[mt], bf[nt], acc[mt][nt], 0, 0, 0);

        // Single barrier: all waves done reading buf[cur] AND (via the
        // compiler's vmcnt(0) drain) stage t+1 is complete in buf[cur^1].
        __syncthreads();
    }
#undef STAGE

    // Epilogue: C/D layout: col = lane&15, row = quad*4 + reg.
    const int s_base = bm * BM + wm * 64;
    const int n_base = bn * BN + wn * 128;
#pragma unroll
    for (int mt = 0; mt < 4; mt++) {
#pragma unroll
        for (int r = 0; r < 4; r++) {
            int s = s_base + mt * 16 + quad * 4 + r;
            float rs = sx[s] / sy[s];
            float* orow = out + (size_t)s * N_DIM;
#pragma unroll
            for (int nt = 0; nt < 8; nt++) {
                int n = n_base + nt * 16 + l16;
                float v = rintf((float)acc[mt][nt][r] * (rs * sw[n]));
                v = fminf(fmaxf(v, -128.f), 127.f);
                orow[n] = v;
            }
        }
    }
}

// ---------------------------------------------------------------------------
// Correctness fallback if the workspace is too small for packed operands.
__global__ void gemm_naive(const int* __restrict__ x, const int* __restrict__ w,
                           const float* __restrict__ sx, const float* __restrict__ sw,
                           const float* __restrict__ sy, float* __restrict__ out) {
    int n = blockIdx.x * blockDim.x + threadIdx.x;
    int s = blockIdx.y;
    const int4* xr = (const int4*)(x + (size_t)s * K_DIM);
    const int4* wr = (const int4*)(w + (size_t)n * K_DIM);
    int acc = 0;
    for (int k = 0; k < K_DIM / 4; k++) {
        int4 a = xr[k], b = wr[k];
        acc += a.x * b.x + a.y * b.y + a.z * b.z + a.w * b.w;
    }
    float v = rintf((float)acc * (sx[s] / sy[s] * sw[n]));
    out[(size_t)s * N_DIM + n] = fminf(fmaxf(v, -128.f), 127.f);
}

// ---------------------------------------------------------------------------
extern "C" void kernel_launch(void* const* d_in, const int* in_sizes, int n_in,
                              void* d_out, int out_size, void* d_ws, size_t ws_size,
                              hipStream_t stream) {
    const int*   x  = (const int*)d_in[0];     // [S, K] int8 values widened to int32
    const int*   wq = (const int*)d_in[1];     // [N, K]
    const float* sx = (const float*)d_in[2];   // [S]
    const float* sw = (const float*)d_in[3];   // [N]
    const float* sy = (const float*)d_in[4];   // [S]
    float* out = (float*)d_out;                // [S*N out_q] ++ [S scale_y], float32

    const size_t need = (size_t)S_DIM * K_DIM + (size_t)N_DIM * K_DIM;  // 48 MiB
    if (ws_size >= need) {
        signed char* xp = (signed char*)d_ws;
        signed char* wp = xp + (size_t)S_DIM * K_DIM;
        const int nprep = (S_DIM * K_DIM / 4) + (N_DIM * K_DIM / 4) + S_DIM;
        prep<<<dim3((nprep + 255) / 256), dim3(256), 0, stream>>>(
            x, wq, sy, (int*)xp, out);
        gemm_i8<<<dim3(N_DIM / BN, S_DIM / BM), dim3(256), 0, stream>>>(
            xp, wp, sx, sw, sy, out);
    } else {
        copy_sy<<<dim3((S_DIM + 255) / 256), dim3(256), 0, stream>>>(sy, out);
        gemm_naive<<<dim3(N_DIM / 256, S_DIM), dim3(256), 0, stream>>>(
            x, wq, sx, sw, sy, out);
    }
}

// Round 7
// 386.132 us; speedup vs baseline: 1.0456x; 1.0415x over previous
//
#include <hip/hip_runtime.h>
#include <stdint.h>

#define S_DIM 8192
#define K_DIM 4096
#define N_DIM 4096

#define BM 128
#define BN 256
#define BK 128   // bytes of K per staging stage (2 MFMA k-steps of 64)

typedef int v4i __attribute__((ext_vector_type(4)));

// ---------------------------------------------------------------------------
// One launch: pack x (int32->int8), pack w, and copy scale_y to the output
// tail. Pack destination is contiguous in ws: [x packed | w packed].
__global__ void prep(const int* __restrict__ x, const int* __restrict__ w,
                     const float* __restrict__ sy,
                     int* __restrict__ dst, float* __restrict__ out) {
    const int nx = S_DIM * K_DIM / 4;
    const int nw = N_DIM * K_DIM / 4;
    int i = blockIdx.x * 256 + threadIdx.x;
    if (i < nx) {
        int4 a = ((const int4*)x)[i];
        dst[i] = (a.x & 0xFF) | ((a.y & 0xFF) << 8) | ((a.z & 0xFF) << 16)
               | ((a.w & 0xFF) << 24);
    } else if (i < nx + nw) {
        int4 a = ((const int4*)w)[i - nx];
        dst[i] = (a.x & 0xFF) | ((a.y & 0xFF) << 8) | ((a.z & 0xFF) << 16)
               | ((a.w & 0xFF) << 24);
    } else {
        int j = i - nx - nw;
        if (j < S_DIM) out[(size_t)S_DIM * N_DIM + j] = sy[j];
    }
}

// scale_y tail only (used by the no-workspace fallback path)
__global__ void copy_sy(const float* __restrict__ sy, float* __restrict__ out) {
    int i = blockIdx.x * blockDim.x + threadIdx.x;
    if (i < S_DIM) out[(size_t)S_DIM * N_DIM + i] = sy[i];
}

// ---------------------------------------------------------------------------
__device__ __forceinline__ void g2lds16(const void* g, void* l) {
    __builtin_amdgcn_global_load_lds((const __attribute__((address_space(1))) void*)g,
                                     (__attribute__((address_space(3))) void*)l,
                                     16, 0, 0);
}

// ---------------------------------------------------------------------------
// 128x256 tile i8 MFMA GEMM — byte-identical to the proven 131-us R0/R4
// kernel (4 waves 2x2, each wave 64m x 128n as 4x8 tiles of
// mfma_i32_16x16x64_i8, global_load_lds staging, XOR-swizzled LDS,
// 2 blocks/CU) EXCEPT one isolated change:
//
// R7: XCD-chunked blockIdx swizzle (T1, reshaped bm-major). Default bn-fast
// dispatch round-robins consecutive blocks over the 8 XCDs, so every XCD's
// 4-MiB L2 sees all 16 B panels (16 MB) -> B staging DMA is served from
// L3/HBM (FETCH 148 MB vs 48 MB unique; ~400-900cy) and that latency is
// exactly what each __syncthreads vmcnt(0) drain eats, 32x/block. Remap
// f -> j = (f&7)*128 + f>>3 (bijective, 1024%8==0), j interpreted bm-major:
// XCD x gets j in [128x, 128x+128) -> bn in {2x, 2x+1} -> 2 MB of B panels
// resident in its L2 across its whole schedule. A (32 MB) stays L3-served.
//
// Schedule levers are exhausted per the R1-R6 ledger: 8-phase ring (R1,R2),
// occupancy push (R3: acc spill), frag hoist (R4: 108+48+128 > 256 regs),
// 32x32 shape (R5: conflicts), 2-deep dbuf (R6: drains fresh loads).
__launch_bounds__(256, 2)
__global__ void gemm_i8(const signed char* __restrict__ xp,
                        const signed char* __restrict__ wp,
                        const float* __restrict__ sx,
                        const float* __restrict__ sw,
                        const float* __restrict__ sy,
                        float* __restrict__ out) {
    __shared__ __align__(16) signed char As[BM * BK];   // 16 KB
    __shared__ __align__(16) signed char Bs[BN * BK];   // 32 KB

    const int tid  = threadIdx.x;
    const int lane = tid & 63;
    const int quad = lane >> 4;    // 0..3 -> 16B k-chunk within a 64B k-step
    const int l16  = lane & 15;    // row (A) / col (B) within 16
    const int wave = tid >> 6;     // 0..3
    const int wm = wave >> 1;      // wave m (2): 64-row slab
    const int wn = wave & 1;       // wave n (2): 128-col slab

    // XCD-chunked swizzle: f in dispatch order (x fast) -> XCD f&7 (round-
    // robin, m157/m192-validated pattern) -> give it a contiguous bm-major
    // chunk so its L2 holds only bn in {2x, 2x+1}.
    const int f  = blockIdx.y * (N_DIM / BN) + blockIdx.x;
    const int j  = (f & 7) * 128 + (f >> 3);
    const int bn = j >> 6;         // [0,16)
    const int bm = j & 63;         // [0,64)

    const signed char* aG = xp + (size_t)(bm * BM) * K_DIM;
    const signed char* bG = wp + (size_t)(bn * BN) * K_DIM;

    const int csw = l16 & 7;       // fragment-read swizzle component

    // Hoisted per-thread staging offsets (loop-invariant): A = 1024 chunks,
    // B = 2048 chunks of 16B; thread handles 4 A + 8 B chunks per stage.
    int aOff[4], bOff[8];
#pragma unroll
    for (int i = 0; i < 4; i++) {
        int li = i * 256 + tid;
        int row = li >> 3, c = li & 7, g = c ^ (row & 7);
        aOff[i] = row * K_DIM + (g << 4);
    }
#pragma unroll
    for (int i = 0; i < 8; i++) {
        int li = i * 256 + tid;
        int row = li >> 3, c = li & 7, g = c ^ (row & 7);
        bOff[i] = row * K_DIM + (g << 4);
    }

    v4i acc[4][8];
#pragma unroll
    for (int i = 0; i < 4; i++)
#pragma unroll
        for (int j2 = 0; j2 < 8; j2++) acc[i][j2] = 0;

    const int slot0 = (0 | quad) ^ csw;            // ks=0 swizzled k-chunk
    const int slot1 = (4 | quad) ^ csw;            // ks=1 swizzled k-chunk
    const signed char* aBase = As + (wm * 64 + l16) * BK;
    const signed char* bBase = Bs + (wn * 128 + l16) * BK;

    for (int kk = 0; kk < K_DIM; kk += BK) {
        __syncthreads();  // protect LDS from previous iteration's readers
#pragma unroll
        for (int i = 0; i < 4; i++)
            g2lds16(aG + aOff[i] + kk, As + (i * 256 + tid) * 16);
#pragma unroll
        for (int i = 0; i < 8; i++)
            g2lds16(bG + bOff[i] + kk, Bs + (i * 256 + tid) * 16);
        __syncthreads();  // vmcnt(0) drain: staging complete

        v4i af0[4], bf0[8], af1[4], bf1[8];
#pragma unroll
        for (int t = 0; t < 4; t++)
            af0[t] = *(const v4i*)(aBase + t * (16 * BK) + (slot0 << 4));
#pragma unroll
        for (int u = 0; u < 8; u++)
            bf0[u] = *(const v4i*)(bBase + u * (16 * BK) + (slot0 << 4));
#pragma unroll
        for (int t = 0; t < 4; t++)
            af1[t] = *(const v4i*)(aBase + t * (16 * BK) + (slot1 << 4));
#pragma unroll
        for (int u = 0; u < 8; u++)
            bf1[u] = *(const v4i*)(bBase + u * (16 * BK) + (slot1 << 4));

#pragma unroll
        for (int mt = 0; mt < 4; mt++)
#pragma unroll
            for (int nt = 0; nt < 8; nt++)
                acc[mt][nt] = __builtin_amdgcn_mfma_i32_16x16x64_i8(
                    af0[mt], bf0[nt], acc[mt][nt], 0, 0, 0);
#pragma unroll
        for (int mt = 0; mt < 4; mt++)
#pragma unroll
            for (int nt = 0; nt < 8; nt++)
                acc[mt][nt] = __builtin_amdgcn_mfma_i32_16x16x64_i8(
                    af1[mt], bf1[nt], acc[mt][nt], 0, 0, 0);
    }

    // Epilogue: C/D layout: col = lane&15, row = quad*4 + reg.
    const int s_base = bm * BM + wm * 64;
    const int n_base = bn * BN + wn * 128;
#pragma unroll
    for (int mt = 0; mt < 4; mt++) {
#pragma unroll
        for (int r = 0; r < 4; r++) {
            int s = s_base + mt * 16 + quad * 4 + r;
            float rs = sx[s] / sy[s];
            float* orow = out + (size_t)s * N_DIM;
#pragma unroll
            for (int nt = 0; nt < 8; nt++) {
                int n = n_base + nt * 16 + l16;
                float v = rintf((float)acc[mt][nt][r] * (rs * sw[n]));
                v = fminf(fmaxf(v, -128.f), 127.f);
                orow[n] = v;
            }
        }
    }
}

// ---------------------------------------------------------------------------
// Correctness fallback if the workspace is too small for packed operands.
__global__ void gemm_naive(const int* __restrict__ x, const int* __restrict__ w,
                           const float* __restrict__ sx, const float* __restrict__ sw,
                           const float* __restrict__ sy, float* __restrict__ out) {
    int n = blockIdx.x * blockDim.x + threadIdx.x;
    int s = blockIdx.y;
    const int4* xr = (const int4*)(x + (size_t)s * K_DIM);
    const int4* wr = (const int4*)(w + (size_t)n * K_DIM);
    int acc = 0;
    for (int k = 0; k < K_DIM / 4; k++) {
        int4 a = xr[k], b = wr[k];
        acc += a.x * b.x + a.y * b.y + a.z * b.z + a.w * b.w;
    }
    float v = rintf((float)acc * (sx[s] / sy[s] * sw[n]));
    out[(size_t)s * N_DIM + n] = fminf(fmaxf(v, -128.f), 127.f);
}

// ---------------------------------------------------------------------------
extern "C" void kernel_launch(void* const* d_in, const int* in_sizes, int n_in,
                              void* d_out, int out_size, void* d_ws, size_t ws_size,
                              hipStream_t stream) {
    const int*   x  = (const int*)d_in[0];     // [S, K] int8 values widened to int32
    const int*   wq = (const int*)d_in[1];     // [N, K]
    const float* sx = (const float*)d_in[2];   // [S]
    const float* sw = (const float*)d_in[3];   // [N]
    const float* sy = (const float*)d_in[4];   // [S]
    float* out = (float*)d_out;                // [S*N out_q] ++ [S scale_y], float32

    const size_t need = (size_t)S_DIM * K_DIM + (size_t)N_DIM * K_DIM;  // 48 MiB
    if (ws_size >= need) {
        signed char* xp = (signed char*)d_ws;
        signed char* wp = xp + (size_t)S_DIM * K_DIM;
        const int nprep = (S_DIM * K_DIM / 4) + (N_DIM * K_DIM / 4) + S_DIM;
        prep<<<dim3((nprep + 255) / 256), dim3(256), 0, stream>>>(
            x, wq, sy, (int*)xp, out);
        gemm_i8<<<dim3(N_DIM / BN, S_DIM / BM), dim3(256), 0, stream>>>(
            xp, wp, sx, sw, sy, out);
    } else {
        copy_sy<<<dim3((S_DIM + 255) / 256), dim3(256), 0, stream>>>(sy, out);
        gemm_naive<<<dim3(N_DIM / 256, S_DIM), dim3(256), 0, stream>>>(
            x, wq, sx, sw, sy, out);
    }
}